// Round 7
// baseline (18.884 us; speedup 1.0000x reference)
//
#include <hip/hip_runtime.h>
#include <utility>

// Geometric product in Cl(3,2,1), DIM=64.
// out[n,k] = sum_a sign(a, a^k) * x[n,a] * y[n,a^k]
//
// Barrier-free, LDS-free design. k-halfspace split by null-dim structure:
//   k < 32  (k bit5=0): sign=0 unless a<32  -> 32x32 = 1024 live FMAs,
//                       touches only x[0:32), y[0:32)
//   k >= 32 (k bit5=1): never annihilates   -> 64x32 = 2048 live FMAs
// One thread = one batch row x one k-half; x,y rows register-resident
// (f4 loads, constant offsets); fully-unrolled constant-sign FMA core
// (signs fold to fneg modifiers); 8x f4 stores of a contiguous 128 B
// output half. No __syncthreads, no LDS, no transpose: single-phase,
// load/compute/store overlap across waves naturally.
// half = wave_id & 1 -> wave-uniform template dispatch, zero divergence.

__host__ __device__ constexpr int popc6(int v) {
  int c = 0;
  for (int i = 0; i < 6; ++i) c += (v >> i) & 1;
  return c;
}

// Faithful to reference _cayley_tables(3,2,1): swap parity, (-1) per shared
// negative dim (bits 3,4), annihilation on shared null dim (bit 5).
__host__ __device__ constexpr float sign_ab(int a, int b) {
  int sw = 0;
  for (int bit = 0; bit < 6; ++bit)
    if ((a >> bit) & 1) sw += popc6(b & ((1 << bit) - 1));
  float s = (sw & 1) ? -1.0f : 1.0f;
  if (popc6(a & b & 0x18) & 1) s = -s;
  if (a & b & 0x20) s = 0.0f;
  return s;
}

// ---- compile-time FMA folds: constant indices only (promotion-safe) ----
template <int HALF, int A, int KK>
__device__ __forceinline__ void term(const float (&xv)[64], const float (&yv)[64],
                                     float (&acc)[32]) {
  constexpr int k = 32 * HALF + KK;
  constexpr int b = A ^ k;
  constexpr float sg = sign_ab(A, b);
  if constexpr (sg > 0.0f)      acc[KK] = fmaf( xv[A], yv[b], acc[KK]);
  else if constexpr (sg < 0.0f) acc[KK] = fmaf(-xv[A], yv[b], acc[KK]);
  // sg == 0: no code
}

template <int HALF, int A, int... KK>
__device__ __forceinline__ void terms(const float (&xv)[64], const float (&yv)[64],
                                      float (&acc)[32], std::integer_sequence<int, KK...>) {
  (term<HALF, A, KK>(xv, yv, acc), ...);
}

template <int HALF, int... A>
__device__ __forceinline__ void core(const float (&xv)[64], const float (&yv)[64],
                                     float (&acc)[32], std::integer_sequence<int, A...>) {
  (terms<HALF, A>(xv, yv, acc, std::make_integer_sequence<int, 32>{}), ...);
}

template <int HALF>
__device__ __forceinline__ void run(const float* __restrict__ xrow,
                                    const float* __restrict__ yrow,
                                    float* __restrict__ orow) {
  constexpr int NA = HALF ? 64 : 32;  // HALF=0: a>=32 all annihilate
  constexpr int NF4 = NA / 4;
  const float4* x4 = (const float4*)xrow;
  const float4* y4 = (const float4*)yrow;
  float xv[64], yv[64];
#pragma unroll
  for (int j = 0; j < NF4; ++j) {  // constant offsets -> global_load_dwordx4 imm
    const float4 tx = x4[j];
    const float4 ty = y4[j];
    xv[4 * j + 0] = tx.x; xv[4 * j + 1] = tx.y; xv[4 * j + 2] = tx.z; xv[4 * j + 3] = tx.w;
    yv[4 * j + 0] = ty.x; yv[4 * j + 1] = ty.y; yv[4 * j + 2] = ty.z; yv[4 * j + 3] = ty.w;
  }
  float acc[32];
#pragma unroll
  for (int i = 0; i < 32; ++i) acc[i] = 0.0f;
  core<HALF>(xv, yv, acc, std::make_integer_sequence<int, NA>{});
  float4* o4 = (float4*)orow;
#pragma unroll
  for (int j = 0; j < 8; ++j) {
    float4 o;
    o.x = acc[4 * j + 0]; o.y = acc[4 * j + 1]; o.z = acc[4 * j + 2]; o.w = acc[4 * j + 3];
    o4[j] = o;
  }
}

__global__ __launch_bounds__(256, 2)
void clgp_kernel(const float* __restrict__ xg, const float* __restrict__ yg,
                 float* __restrict__ og) {
  const int t = threadIdx.x;
  const int lane = t & 63;       // batch row within the wave's 64-row window
  const int w = t >> 6;          // wave id 0..3
  const int half = w & 1;        // k-half (wave-uniform)
  // waves (0,1) -> rows [blk*128, +64), waves (2,3) -> next 64 rows;
  // the two waves of a pair read the same rows -> L1 dedups the re-read.
  const long n = (long)blockIdx.x * 128 + (w >> 1) * 64 + lane;
  const float* xrow = xg + n * 64;
  const float* yrow = yg + n * 64;
  float* orow = og + n * 64 + 32 * half;  // contiguous 128 B output half
  if (half == 0) run<0>(xrow, yrow, orow);
  else           run<1>(xrow, yrow, orow);
}

extern "C" void kernel_launch(void* const* d_in, const int* in_sizes, int n_in,
                              void* d_out, int out_size, void* d_ws, size_t ws_size,
                              hipStream_t stream) {
  const float* x = (const float*)d_in[0];
  const float* y = (const float*)d_in[1];
  float* out = (float*)d_out;
  const int n_batch = in_sizes[0] / 64;
  const int grid = n_batch / 128;  // 128 rows/block (2 k-halves each) -> 512 blocks
  clgp_kernel<<<grid, 256, 0, stream>>>(x, y, out);
}